// Round 1
// baseline (1460.517 us; speedup 1.0000x reference)
//
#include <hip/hip_runtime.h>
#include <hip/hip_bf16.h>

// Problem constants (reference file)
#define NN 50000
#define F_IN 512
#define HH 128
#define CC 64
#define EE 800000

// ---------------------------------------------------------------------------
// Tiled fp32 GEMM: C[nrows, BN] = A[nrows, K] @ B[K, BN]
// BM=64 rows per block, full output width BN per block, BK=32 K-chunk.
// 256 threads = 16x16; each thread computes 4 rows x (BN/16) cols.
// ---------------------------------------------------------------------------
template <int K, int BN>
__global__ __launch_bounds__(256) void gemm_f32(const float* __restrict__ A,
                                                const float* __restrict__ B,
                                                float* __restrict__ C,
                                                int nrows) {
    constexpr int BM = 64;
    constexpr int BK = 32;
    constexpr int NR = BN / 16;  // cols per thread (8 for BN=128, 4 for BN=64)

    __shared__ float As[BK][BM];      // k-major
    __shared__ float Bs[BK][BN];

    const int tid = threadIdx.x;
    const int tx = tid & 15;          // col group 0..15
    const int ty = tid >> 4;          // row group 0..15
    const int m0 = blockIdx.x * BM;

    float acc[4][NR];
#pragma unroll
    for (int r = 0; r < 4; ++r)
#pragma unroll
        for (int c = 0; c < NR; ++c) acc[r][c] = 0.f;

    for (int k0 = 0; k0 < K; k0 += BK) {
        // --- load A tile (BM x BK), float4 along k ---
#pragma unroll
        for (int p = 0; p < (BM * BK / 4) / 256; ++p) {   // 2 passes
            int idx = p * 256 + tid;
            int m = idx >> 3;         // 0..63
            int kq = idx & 7;         // float4 index within BK
            int row = m0 + m;
            if (row >= nrows) row = nrows - 1;            // clamp (discarded on store)
            const float4 v = *reinterpret_cast<const float4*>(
                &A[(size_t)row * K + k0 + kq * 4]);
            As[kq * 4 + 0][m] = v.x;
            As[kq * 4 + 1][m] = v.y;
            As[kq * 4 + 2][m] = v.z;
            As[kq * 4 + 3][m] = v.w;
        }
        // --- load B tile (BK x BN) ---
#pragma unroll
        for (int p = 0; p < (BK * BN / 4) / 256; ++p) {
            int idx = p * 256 + tid;
            int cq = idx % (BN / 4);
            int kk = idx / (BN / 4);
            const float4 v = *reinterpret_cast<const float4*>(
                &B[(size_t)(k0 + kk) * BN + cq * 4]);
            *reinterpret_cast<float4*>(&Bs[kk][cq * 4]) = v;
        }
        __syncthreads();

#pragma unroll
        for (int kk = 0; kk < BK; ++kk) {
            const float4 a4 = *reinterpret_cast<const float4*>(&As[kk][ty * 4]);
            float a[4] = {a4.x, a4.y, a4.z, a4.w};
            float b[NR];
#pragma unroll
            for (int cq = 0; cq < NR / 4; ++cq) {
                const float4 b4 = *reinterpret_cast<const float4*>(
                    &Bs[kk][tx * NR + cq * 4]);
                b[cq * 4 + 0] = b4.x; b[cq * 4 + 1] = b4.y;
                b[cq * 4 + 2] = b4.z; b[cq * 4 + 3] = b4.w;
            }
#pragma unroll
            for (int r = 0; r < 4; ++r)
#pragma unroll
                for (int c = 0; c < NR; ++c) acc[r][c] += a[r] * b[c];
        }
        __syncthreads();
    }

    // --- store ---
#pragma unroll
    for (int r = 0; r < 4; ++r) {
        int row = m0 + ty * 4 + r;
        if (row < nrows) {
#pragma unroll
            for (int c = 0; c < NR; ++c)
                C[(size_t)row * BN + tx * NR + c] = acc[r][c];
        }
    }
}

// ---------------------------------------------------------------------------
// SpMM via atomic scatter: Y[row[e]] += val[e] * X[col[e]]   (Y pre-zeroed)
// One 64-lane wave per edge; H/64 floats per lane.
// ---------------------------------------------------------------------------
template <int H>
__global__ __launch_bounds__(256) void spmm_scatter(const int* __restrict__ row,
                                                    const int* __restrict__ col,
                                                    const float* __restrict__ val,
                                                    const float* __restrict__ X,
                                                    float* __restrict__ Y,
                                                    int nedges) {
    const int gtid = blockIdx.x * blockDim.x + threadIdx.x;
    const int e = gtid >> 6;
    const int lane = gtid & 63;
    if (e >= nedges) return;
    const int r = row[e];
    const int c = col[e];
    const float v = val[e];
#pragma unroll
    for (int j = 0; j < H / 64; ++j) {
        const int f = lane + j * 64;
        atomicAdd(&Y[(size_t)r * H + f], v * X[(size_t)c * H + f]);
    }
}

// Y = relu(A - Y), elementwise
__global__ __launch_bounds__(256) void relu_sub(const float* __restrict__ A,
                                                float* __restrict__ Y, int n) {
    int i = blockIdx.x * blockDim.x + threadIdx.x;
    if (i < n) {
        float v = A[i] - Y[i];
        Y[i] = v > 0.f ? v : 0.f;
    }
}

__device__ __forceinline__ float wave_sum(float v) {
#pragma unroll
    for (int off = 32; off > 0; off >>= 1) v += __shfl_xor(v, off, 64);
    return v;
}
__device__ __forceinline__ float wave_max(float v) {
#pragma unroll
    for (int off = 32; off > 0; off >>= 1) v = fmaxf(v, __shfl_xor(v, off, 64));
    return v;
}

// ---------------------------------------------------------------------------
// Layer-1 fused: relu(spmm_l), o_high (pre-relu'd), relu(xm) -> attention ->
// h = 3*(al*o_low + ah*o_high + am*o_mlp), written in-place into spmm_l buffer.
// One wave per node, H=128 -> 2 features per lane.
// ---------------------------------------------------------------------------
__global__ __launch_bounds__(256) void att_combine1(float* __restrict__ spmm_l,
                                                    const float* __restrict__ o_high,
                                                    const float* __restrict__ xm,
                                                    const float* __restrict__ a_low,
                                                    const float* __restrict__ a_high,
                                                    const float* __restrict__ a_mlp,
                                                    const float* __restrict__ av,
                                                    int n) {
    const int node = blockIdx.x * 4 + (threadIdx.x >> 6);
    const int lane = threadIdx.x & 63;
    if (node >= n) return;
    const size_t base = (size_t)node * HH;

    float ol0 = fmaxf(spmm_l[base + lane], 0.f);
    float ol1 = fmaxf(spmm_l[base + 64 + lane], 0.f);
    float oh0 = o_high[base + lane];
    float oh1 = o_high[base + 64 + lane];
    float om0 = fmaxf(xm[base + lane], 0.f);
    float om1 = fmaxf(xm[base + 64 + lane], 0.f);

    float dl = ol0 * a_low[lane] + ol1 * a_low[64 + lane];
    float dh = oh0 * a_high[lane] + oh1 * a_high[64 + lane];
    float dm = om0 * a_mlp[lane] + om1 * a_mlp[64 + lane];
    dl = wave_sum(dl);
    dh = wave_sum(dh);
    dm = wave_sum(dm);

    const float g0 = 1.f / (1.f + expf(-dl));
    const float g1 = 1.f / (1.f + expf(-dh));
    const float g2 = 1.f / (1.f + expf(-dm));
    float s0 = (g0 * av[0] + g1 * av[3] + g2 * av[6]) * (1.f / 3.f);
    float s1 = (g0 * av[1] + g1 * av[4] + g2 * av[7]) * (1.f / 3.f);
    float s2 = (g0 * av[2] + g1 * av[5] + g2 * av[8]) * (1.f / 3.f);
    float mx = fmaxf(s0, fmaxf(s1, s2));
    float e0 = expf(s0 - mx), e1 = expf(s1 - mx), e2 = expf(s2 - mx);
    float inv = 1.f / (e0 + e1 + e2);
    float at0 = e0 * inv, at1 = e1 * inv, at2 = e2 * inv;

    spmm_l[base + lane]      = 3.f * (at0 * ol0 + at1 * oh0 + at2 * om0);
    spmm_l[base + 64 + lane] = 3.f * (at0 * ol1 + at1 * oh1 + at2 * om1);
}

// ---------------------------------------------------------------------------
// Layer-2 fused: attention + combine + log_softmax -> d_out. C=64, 1 feat/lane.
// ---------------------------------------------------------------------------
__global__ __launch_bounds__(256) void att_combine2(const float* __restrict__ spmm_l,
                                                    const float* __restrict__ o_high,
                                                    const float* __restrict__ xm,
                                                    const float* __restrict__ a_low,
                                                    const float* __restrict__ a_high,
                                                    const float* __restrict__ a_mlp,
                                                    const float* __restrict__ av,
                                                    float* __restrict__ out,
                                                    int n) {
    const int node = blockIdx.x * 4 + (threadIdx.x >> 6);
    const int lane = threadIdx.x & 63;
    if (node >= n) return;
    const size_t base = (size_t)node * CC;

    float ol = fmaxf(spmm_l[base + lane], 0.f);
    float oh = o_high[base + lane];
    float om = fmaxf(xm[base + lane], 0.f);

    float dl = wave_sum(ol * a_low[lane]);
    float dh = wave_sum(oh * a_high[lane]);
    float dm = wave_sum(om * a_mlp[lane]);

    const float g0 = 1.f / (1.f + expf(-dl));
    const float g1 = 1.f / (1.f + expf(-dh));
    const float g2 = 1.f / (1.f + expf(-dm));
    float s0 = (g0 * av[0] + g1 * av[3] + g2 * av[6]) * (1.f / 3.f);
    float s1 = (g0 * av[1] + g1 * av[4] + g2 * av[7]) * (1.f / 3.f);
    float s2 = (g0 * av[2] + g1 * av[5] + g2 * av[8]) * (1.f / 3.f);
    float mx3 = fmaxf(s0, fmaxf(s1, s2));
    float e0 = expf(s0 - mx3), e1 = expf(s1 - mx3), e2 = expf(s2 - mx3);
    float inv = 1.f / (e0 + e1 + e2);
    float at0 = e0 * inv, at1 = e1 * inv, at2 = e2 * inv;

    float o = 3.f * (at0 * ol + at1 * oh + at2 * om);

    // log_softmax over the 64 classes (one per lane)
    float m = wave_max(o);
    float ex = expf(o - m);
    float s = wave_sum(ex);
    out[base + lane] = o - m - logf(s);
}

// ---------------------------------------------------------------------------
extern "C" void kernel_launch(void* const* d_in, const int* in_sizes, int n_in,
                              void* d_out, int out_size, void* d_ws, size_t ws_size,
                              hipStream_t stream) {
    const float* x    = (const float*)d_in[0];
    const int*   erow = (const int*)d_in[1];
    const int*   ecol = (const int*)d_in[2];
    const float* eval = (const float*)d_in[3];
    const float* Wl   = (const float*)d_in[4];
    const float* Wh   = (const float*)d_in[5];
    const float* Wm   = (const float*)d_in[6];
    const float* al   = (const float*)d_in[7];
    const float* ah   = (const float*)d_in[8];
    const float* am   = (const float*)d_in[9];
    const float* av   = (const float*)d_in[10];
    const float* Wl2  = (const float*)d_in[11];
    const float* Wh2  = (const float*)d_in[12];
    const float* Wm2  = (const float*)d_in[13];
    const float* al2  = (const float*)d_in[14];
    const float* ah2  = (const float*)d_in[15];
    const float* am2  = (const float*)d_in[16];
    const float* av2  = (const float*)d_in[17];
    float* out = (float*)d_out;

    const int E = in_sizes[1];
    const int N = NN;

    float* ws   = (float*)d_ws;
    float* bufA = ws;                     // N*HH
    float* bufB = ws + (size_t)N * HH;    // N*HH  (spmm_l -> h)
    float* bufC = ws + (size_t)2 * N * HH;// N*HH  (spmm_h -> o_high)

    const int gemm_blocks = (N + 63) / 64;
    const int spmm_blocks = (E * 64 + 255) / 256;
    const int elem1_blocks = (N * HH + 255) / 256;
    const int elem2_blocks = (N * CC + 255) / 256;
    const int node_blocks = (N + 3) / 4;

    // ---------------- Layer 1 ----------------
    // xh
    gemm_f32<F_IN, HH><<<gemm_blocks, 256, 0, stream>>>(x, Wh, bufA, N);
    hipMemsetAsync(bufC, 0, (size_t)N * HH * sizeof(float), stream);
    spmm_scatter<HH><<<spmm_blocks, 256, 0, stream>>>(erow, ecol, eval, bufA, bufC, E);
    relu_sub<<<elem1_blocks, 256, 0, stream>>>(bufA, bufC, N * HH);    // o_high
    // xl
    gemm_f32<F_IN, HH><<<gemm_blocks, 256, 0, stream>>>(x, Wl, bufA, N);
    hipMemsetAsync(bufB, 0, (size_t)N * HH * sizeof(float), stream);
    spmm_scatter<HH><<<spmm_blocks, 256, 0, stream>>>(erow, ecol, eval, bufA, bufB, E);
    // xm
    gemm_f32<F_IN, HH><<<gemm_blocks, 256, 0, stream>>>(x, Wm, bufA, N);
    // fused attention + combine -> h in bufB
    att_combine1<<<node_blocks, 256, 0, stream>>>(bufB, bufC, bufA, al, ah, am, av, N);

    // ---------------- Layer 2 ----------------
    float* l2a = bufA;                    // N*CC
    float* l2b = bufA + (size_t)N * CC;   // N*CC
    float* l2c = bufC;                    // N*CC

    // xh2
    gemm_f32<HH, CC><<<gemm_blocks, 256, 0, stream>>>(bufB, Wh2, l2a, N);
    hipMemsetAsync(l2b, 0, (size_t)N * CC * sizeof(float), stream);
    spmm_scatter<CC><<<spmm_blocks, 256, 0, stream>>>(erow, ecol, eval, l2a, l2b, E);
    relu_sub<<<elem2_blocks, 256, 0, stream>>>(l2a, l2b, N * CC);      // o_high2
    // xl2
    gemm_f32<HH, CC><<<gemm_blocks, 256, 0, stream>>>(bufB, Wl2, l2a, N);
    hipMemsetAsync(l2c, 0, (size_t)N * CC * sizeof(float), stream);
    spmm_scatter<CC><<<spmm_blocks, 256, 0, stream>>>(erow, ecol, eval, l2a, l2c, E);
    // xm2
    gemm_f32<HH, CC><<<gemm_blocks, 256, 0, stream>>>(bufB, Wm2, l2a, N);
    // fused attention + combine + log_softmax -> out
    att_combine2<<<node_blocks, 256, 0, stream>>>(l2c, l2b, l2a, al2, ah2, am2, av2, out, N);
}

// Round 2
// 773.339 us; speedup vs baseline: 1.8886x; 1.8886x over previous
//
#include <hip/hip_runtime.h>
#include <hip/hip_bf16.h>

// Problem constants (reference file)
#define NN 50000
#define F_IN 512
#define HH 128
#define CC 64

// ---------------------------------------------------------------------------
// Tiled fp32 GEMM: C[nrows, BN] = A[nrows, K] @ B[K, BN]
// ---------------------------------------------------------------------------
template <int K, int BN>
__global__ __launch_bounds__(256) void gemm_f32(const float* __restrict__ A,
                                                const float* __restrict__ B,
                                                float* __restrict__ C,
                                                int nrows) {
    constexpr int BM = 64;
    constexpr int BK = 32;
    constexpr int NR = BN / 16;

    __shared__ float As[BK][BM];
    __shared__ float Bs[BK][BN];

    const int tid = threadIdx.x;
    const int tx = tid & 15;
    const int ty = tid >> 4;
    const int m0 = blockIdx.x * BM;

    float acc[4][NR];
#pragma unroll
    for (int r = 0; r < 4; ++r)
#pragma unroll
        for (int c = 0; c < NR; ++c) acc[r][c] = 0.f;

    for (int k0 = 0; k0 < K; k0 += BK) {
#pragma unroll
        for (int p = 0; p < (BM * BK / 4) / 256; ++p) {
            int idx = p * 256 + tid;
            int m = idx >> 3;
            int kq = idx & 7;
            int row = m0 + m;
            if (row >= nrows) row = nrows - 1;
            const float4 v = *reinterpret_cast<const float4*>(
                &A[(size_t)row * K + k0 + kq * 4]);
            As[kq * 4 + 0][m] = v.x;
            As[kq * 4 + 1][m] = v.y;
            As[kq * 4 + 2][m] = v.z;
            As[kq * 4 + 3][m] = v.w;
        }
#pragma unroll
        for (int p = 0; p < (BK * BN / 4) / 256; ++p) {
            int idx = p * 256 + tid;
            int cq = idx % (BN / 4);
            int kk = idx / (BN / 4);
            const float4 v = *reinterpret_cast<const float4*>(
                &B[(size_t)(k0 + kk) * BN + cq * 4]);
            *reinterpret_cast<float4*>(&Bs[kk][cq * 4]) = v;
        }
        __syncthreads();

#pragma unroll
        for (int kk = 0; kk < BK; ++kk) {
            const float4 a4 = *reinterpret_cast<const float4*>(&As[kk][ty * 4]);
            float a[4] = {a4.x, a4.y, a4.z, a4.w};
            float b[NR];
#pragma unroll
            for (int cq = 0; cq < NR / 4; ++cq) {
                const float4 b4 = *reinterpret_cast<const float4*>(
                    &Bs[kk][tx * NR + cq * 4]);
                b[cq * 4 + 0] = b4.x; b[cq * 4 + 1] = b4.y;
                b[cq * 4 + 2] = b4.z; b[cq * 4 + 3] = b4.w;
            }
#pragma unroll
            for (int r = 0; r < 4; ++r)
#pragma unroll
                for (int c = 0; c < NR; ++c) acc[r][c] += a[r] * b[c];
        }
        __syncthreads();
    }

#pragma unroll
    for (int r = 0; r < 4; ++r) {
        int row = m0 + ty * 4 + r;
        if (row < nrows) {
#pragma unroll
            for (int c = 0; c < NR; ++c)
                C[(size_t)row * BN + tx * NR + c] = acc[r][c];
        }
    }
}

// ---------------------------------------------------------------------------
// CSR construction: histogram -> 2-level exclusive scan -> position scatter
// ---------------------------------------------------------------------------
__global__ __launch_bounds__(256) void hist_kernel(const int* __restrict__ row,
                                                   int* __restrict__ counts, int E) {
    int i = blockIdx.x * 256 + threadIdx.x;
    if (i < E) atomicAdd(&counts[row[i]], 1);
}

__global__ __launch_bounds__(256) void block_sums_kernel(const int* __restrict__ counts,
                                                         int* __restrict__ bsums, int n) {
    __shared__ int s[256];
    int tid = threadIdx.x;
    int i = blockIdx.x * 256 + tid;
    s[tid] = (i < n) ? counts[i] : 0;
    __syncthreads();
#pragma unroll
    for (int off = 128; off > 0; off >>= 1) {
        if (tid < off) s[tid] += s[tid + off];
        __syncthreads();
    }
    if (tid == 0) bsums[blockIdx.x] = s[0];
}

__global__ __launch_bounds__(64) void scan_bsums_kernel(int* __restrict__ bsums, int nb) {
    if (threadIdx.x == 0) {
        int a = 0;
        for (int i = 0; i < nb; ++i) {
            int t = bsums[i];
            bsums[i] = a;
            a += t;
        }
    }
}

__global__ __launch_bounds__(256) void scan_final_kernel(const int* __restrict__ counts,
                                                         const int* __restrict__ bsums,
                                                         int* __restrict__ rowptr,
                                                         int* __restrict__ cursor, int n) {
    __shared__ int s[256];
    int tid = threadIdx.x;
    int i = blockIdx.x * 256 + tid;
    int v = (i < n) ? counts[i] : 0;
    s[tid] = v;
    __syncthreads();
    // Hillis-Steele inclusive scan
#pragma unroll
    for (int off = 1; off < 256; off <<= 1) {
        int t = (tid >= off) ? s[tid - off] : 0;
        __syncthreads();
        s[tid] += t;
        __syncthreads();
    }
    int excl = s[tid] - v + bsums[blockIdx.x];
    if (i < n) {
        rowptr[i] = excl;
        cursor[i] = excl;
        if (i == n - 1) rowptr[n] = excl + v;
    }
}

__global__ __launch_bounds__(256) void scatter_edges_kernel(const int* __restrict__ row,
                                                            const int* __restrict__ col,
                                                            const float* __restrict__ val,
                                                            int* __restrict__ cursor,
                                                            int* __restrict__ cols_s,
                                                            float* __restrict__ vals_s, int E) {
    int i = blockIdx.x * 256 + threadIdx.x;
    if (i < E) {
        int r = row[i];
        int p = atomicAdd(&cursor[r], 1);
        cols_s[p] = col[i];
        vals_s[p] = val[i];
    }
}

// ---------------------------------------------------------------------------
// Pull-based CSR spmm, one wave per row.
// HIGH=false: Y = relu(spmm(X));  HIGH=true: Y = relu(X[row] - spmm(X)).
// ---------------------------------------------------------------------------
template <int H, bool HIGH>
__global__ __launch_bounds__(256) void spmm_csr(const int* __restrict__ rowptr,
                                                const int* __restrict__ cols,
                                                const float* __restrict__ vals,
                                                const float* __restrict__ X,
                                                float* __restrict__ Y, int n) {
    const int node = blockIdx.x * 4 + (threadIdx.x >> 6);
    const int lane = threadIdx.x & 63;
    if (node >= n) return;
    const int s = rowptr[node];
    const int e = rowptr[node + 1];

    float acc[H / 64];
#pragma unroll
    for (int q = 0; q < H / 64; ++q) acc[q] = 0.f;

    for (int b = s; b < e; b += 64) {
        const int idx = b + lane;
        int c = 0;
        float v = 0.f;
        if (idx < e) { c = cols[idx]; v = vals[idx]; }
        const int cnt = min(64, e - b);
        for (int j = 0; j < cnt; ++j) {
            const int cj = __shfl(c, j, 64);
            const float vj = __shfl(v, j, 64);
#pragma unroll
            for (int q = 0; q < H / 64; ++q)
                acc[q] += vj * X[(size_t)cj * H + q * 64 + lane];
        }
    }

#pragma unroll
    for (int q = 0; q < H / 64; ++q) {
        float o;
        if (HIGH)
            o = X[(size_t)node * H + q * 64 + lane] - acc[q];
        else
            o = acc[q];
        Y[(size_t)node * H + q * 64 + lane] = o > 0.f ? o : 0.f;
    }
}

// ---------------------------------------------------------------------------
__device__ __forceinline__ float wave_sum(float v) {
#pragma unroll
    for (int off = 32; off > 0; off >>= 1) v += __shfl_xor(v, off, 64);
    return v;
}
__device__ __forceinline__ float wave_max(float v) {
#pragma unroll
    for (int off = 32; off > 0; off >>= 1) v = fmaxf(v, __shfl_xor(v, off, 64));
    return v;
}

// ---------------------------------------------------------------------------
// Layer-1 fused attention+combine. Inputs already relu'd (relu is idempotent).
// ---------------------------------------------------------------------------
__global__ __launch_bounds__(256) void att_combine1(float* __restrict__ o_low,
                                                    const float* __restrict__ o_high,
                                                    const float* __restrict__ xm,
                                                    const float* __restrict__ a_low,
                                                    const float* __restrict__ a_high,
                                                    const float* __restrict__ a_mlp,
                                                    const float* __restrict__ av,
                                                    int n) {
    const int node = blockIdx.x * 4 + (threadIdx.x >> 6);
    const int lane = threadIdx.x & 63;
    if (node >= n) return;
    const size_t base = (size_t)node * HH;

    float ol0 = o_low[base + lane];
    float ol1 = o_low[base + 64 + lane];
    float oh0 = o_high[base + lane];
    float oh1 = o_high[base + 64 + lane];
    float om0 = fmaxf(xm[base + lane], 0.f);
    float om1 = fmaxf(xm[base + 64 + lane], 0.f);

    float dl = ol0 * a_low[lane] + ol1 * a_low[64 + lane];
    float dh = oh0 * a_high[lane] + oh1 * a_high[64 + lane];
    float dm = om0 * a_mlp[lane] + om1 * a_mlp[64 + lane];
    dl = wave_sum(dl);
    dh = wave_sum(dh);
    dm = wave_sum(dm);

    const float g0 = 1.f / (1.f + expf(-dl));
    const float g1 = 1.f / (1.f + expf(-dh));
    const float g2 = 1.f / (1.f + expf(-dm));
    float s0 = (g0 * av[0] + g1 * av[3] + g2 * av[6]) * (1.f / 3.f);
    float s1 = (g0 * av[1] + g1 * av[4] + g2 * av[7]) * (1.f / 3.f);
    float s2 = (g0 * av[2] + g1 * av[5] + g2 * av[8]) * (1.f / 3.f);
    float mx = fmaxf(s0, fmaxf(s1, s2));
    float e0 = expf(s0 - mx), e1 = expf(s1 - mx), e2 = expf(s2 - mx);
    float inv = 1.f / (e0 + e1 + e2);
    float at0 = e0 * inv, at1 = e1 * inv, at2 = e2 * inv;

    o_low[base + lane]      = 3.f * (at0 * ol0 + at1 * oh0 + at2 * om0);
    o_low[base + 64 + lane] = 3.f * (at0 * ol1 + at1 * oh1 + at2 * om1);
}

// ---------------------------------------------------------------------------
// Layer-2 fused attention+combine+log_softmax -> d_out.
// ---------------------------------------------------------------------------
__global__ __launch_bounds__(256) void att_combine2(const float* __restrict__ o_low,
                                                    const float* __restrict__ o_high,
                                                    const float* __restrict__ xm,
                                                    const float* __restrict__ a_low,
                                                    const float* __restrict__ a_high,
                                                    const float* __restrict__ a_mlp,
                                                    const float* __restrict__ av,
                                                    float* __restrict__ out,
                                                    int n) {
    const int node = blockIdx.x * 4 + (threadIdx.x >> 6);
    const int lane = threadIdx.x & 63;
    if (node >= n) return;
    const size_t base = (size_t)node * CC;

    float ol = o_low[base + lane];
    float oh = o_high[base + lane];
    float om = fmaxf(xm[base + lane], 0.f);

    float dl = wave_sum(ol * a_low[lane]);
    float dh = wave_sum(oh * a_high[lane]);
    float dm = wave_sum(om * a_mlp[lane]);

    const float g0 = 1.f / (1.f + expf(-dl));
    const float g1 = 1.f / (1.f + expf(-dh));
    const float g2 = 1.f / (1.f + expf(-dm));
    float s0 = (g0 * av[0] + g1 * av[3] + g2 * av[6]) * (1.f / 3.f);
    float s1 = (g0 * av[1] + g1 * av[4] + g2 * av[7]) * (1.f / 3.f);
    float s2 = (g0 * av[2] + g1 * av[5] + g2 * av[8]) * (1.f / 3.f);
    float mx3 = fmaxf(s0, fmaxf(s1, s2));
    float e0 = expf(s0 - mx3), e1 = expf(s1 - mx3), e2 = expf(s2 - mx3);
    float inv = 1.f / (e0 + e1 + e2);
    float at0 = e0 * inv, at1 = e1 * inv, at2 = e2 * inv;

    float o = 3.f * (at0 * ol + at1 * oh + at2 * om);

    float m = wave_max(o);
    float ex = expf(o - m);
    float su = wave_sum(ex);
    out[base + lane] = o - m - logf(su);
}

// ---------------------------------------------------------------------------
extern "C" void kernel_launch(void* const* d_in, const int* in_sizes, int n_in,
                              void* d_out, int out_size, void* d_ws, size_t ws_size,
                              hipStream_t stream) {
    const float* x    = (const float*)d_in[0];
    const int*   erow = (const int*)d_in[1];
    const int*   ecol = (const int*)d_in[2];
    const float* eval = (const float*)d_in[3];
    const float* Wl   = (const float*)d_in[4];
    const float* Wh   = (const float*)d_in[5];
    const float* Wm   = (const float*)d_in[6];
    const float* al   = (const float*)d_in[7];
    const float* ah   = (const float*)d_in[8];
    const float* am   = (const float*)d_in[9];
    const float* av   = (const float*)d_in[10];
    const float* Wl2  = (const float*)d_in[11];
    const float* Wh2  = (const float*)d_in[12];
    const float* Wm2  = (const float*)d_in[13];
    const float* al2  = (const float*)d_in[14];
    const float* ah2  = (const float*)d_in[15];
    const float* am2  = (const float*)d_in[16];
    const float* av2  = (const float*)d_in[17];
    float* out = (float*)d_out;

    const int E = in_sizes[1];
    const int N = NN;

    float* ws   = (float*)d_ws;
    float* bufA = ws;                      // N*HH
    float* bufB = ws + (size_t)N * HH;     // N*HH
    float* bufC = ws + (size_t)2 * N * HH; // N*HH

    int* ip = (int*)(ws + (size_t)3 * N * HH);
    int*   counts = ip;                    // N
    int*   rowptr = ip + N;                // N+1
    int*   cursor = ip + 2 * N + 1;        // N
    int*   bsums  = ip + 3 * N + 1;        // 256
    int*   cols_s = ip + 3 * N + 1 + 256;  // E
    float* vals_s = (float*)(cols_s + E);  // E

    const int NB = (N + 255) / 256;        // scan blocks
    const int EB = (E + 255) / 256;
    const int gemm_blocks = (N + 63) / 64;
    const int node_blocks = (N + 3) / 4;

    // ---------------- CSR build (once per launch) ----------------
    hipMemsetAsync(counts, 0, (size_t)N * sizeof(int), stream);
    hist_kernel<<<EB, 256, 0, stream>>>(erow, counts, E);
    block_sums_kernel<<<NB, 256, 0, stream>>>(counts, bsums, N);
    scan_bsums_kernel<<<1, 64, 0, stream>>>(bsums, NB);
    scan_final_kernel<<<NB, 256, 0, stream>>>(counts, bsums, rowptr, cursor, N);
    scatter_edges_kernel<<<EB, 256, 0, stream>>>(erow, ecol, eval, cursor, cols_s, vals_s, E);

    // ---------------- Layer 1 ----------------
    gemm_f32<F_IN, HH><<<gemm_blocks, 256, 0, stream>>>(x, Wh, bufA, N);           // xh
    spmm_csr<HH, true><<<node_blocks, 256, 0, stream>>>(rowptr, cols_s, vals_s,
                                                        bufA, bufC, N);            // o_high
    gemm_f32<F_IN, HH><<<gemm_blocks, 256, 0, stream>>>(x, Wl, bufA, N);           // xl
    spmm_csr<HH, false><<<node_blocks, 256, 0, stream>>>(rowptr, cols_s, vals_s,
                                                         bufA, bufB, N);           // o_low
    gemm_f32<F_IN, HH><<<gemm_blocks, 256, 0, stream>>>(x, Wm, bufA, N);           // xm
    att_combine1<<<node_blocks, 256, 0, stream>>>(bufB, bufC, bufA, al, ah, am, av, N);

    // ---------------- Layer 2 ----------------
    float* l2a = bufA;                    // N*CC
    float* l2b = bufA + (size_t)N * CC;   // N*CC
    float* l2c = bufC;                    // N*CC

    gemm_f32<HH, CC><<<gemm_blocks, 256, 0, stream>>>(bufB, Wh2, l2a, N);          // xh2
    spmm_csr<CC, true><<<node_blocks, 256, 0, stream>>>(rowptr, cols_s, vals_s,
                                                        l2a, l2b, N);              // o_high2
    gemm_f32<HH, CC><<<gemm_blocks, 256, 0, stream>>>(bufB, Wl2, l2a, N);          // xl2
    spmm_csr<CC, false><<<node_blocks, 256, 0, stream>>>(rowptr, cols_s, vals_s,
                                                         l2a, l2c, N);             // o_low2
    gemm_f32<HH, CC><<<gemm_blocks, 256, 0, stream>>>(bufB, Wm2, l2a, N);          // xm2
    att_combine2<<<node_blocks, 256, 0, stream>>>(l2c, l2b, l2a, al2, ah2, am2, av2, out, N);
}

// Round 3
// 435.886 us; speedup vs baseline: 3.3507x; 1.7742x over previous
//
#include <hip/hip_runtime.h>
#include <hip/hip_bf16.h>

// Problem constants (reference file)
#define NN 50000
#define F_IN 512
#define HH 128
#define CC 64

typedef __attribute__((ext_vector_type(8))) short short8v;   // 8 bf16 (4 VGPRs)
typedef __attribute__((ext_vector_type(4))) float f32x4;     // MFMA accumulator

__device__ __forceinline__ short f2b(float f) {
    unsigned u = __builtin_bit_cast(unsigned, f);
    unsigned r = (u + 0x7fffu + ((u >> 16) & 1u)) >> 16;     // RNE
    return (short)r;
}
__device__ __forceinline__ float b2f(short s) {
    unsigned u = ((unsigned)(unsigned short)s) << 16;
    return __builtin_bit_cast(float, u);
}

// ---------------------------------------------------------------------------
// Weight prep: Bt[n][k] = W_{n/OUTW}[k][n%OUTW]  (bf16, transposed + concat)
// ---------------------------------------------------------------------------
template <int K, int OUTW>
__global__ __launch_bounds__(256) void wprep(const float* __restrict__ W0,
                                             const float* __restrict__ W1,
                                             const float* __restrict__ W2,
                                             short* __restrict__ Bt) {
    const int id = blockIdx.x * 256 + threadIdx.x;
    const int nth = 3 * OUTW * (K / 8);
    if (id >= nth) return;
    const int n = id / (K / 8);
    const int kq = id % (K / 8);
    const int sel = n / OUTW;
    const int c = n % OUTW;
    const float* W = sel == 0 ? W0 : (sel == 1 ? W1 : W2);
    short v[8];
#pragma unroll
    for (int j = 0; j < 8; ++j) v[j] = f2b(W[(size_t)(kq * 8 + j) * OUTW + c]);
#pragma unroll
    for (int j = 0; j < 8; ++j) Bt[(size_t)n * K + kq * 8 + j] = v[j];
}

// ---------------------------------------------------------------------------
// Fused MFMA GEMM: C[M, 3*BN] = A[M,K] @ Bt^T, outputs split into O0/O1/O2
// (each M x BN, bf16). A is f32 (converted in staging) if AF32, else bf16.
// BM=128, BK=32, 256 threads (4 waves). mfma_f32_16x16x32_bf16.
// ---------------------------------------------------------------------------
template <int K, int BN, bool AF32>
__global__ __launch_bounds__(256) void gemm_mfma(const void* __restrict__ Avoid,
                                                 const short* __restrict__ Bt,
                                                 short* __restrict__ O0,
                                                 short* __restrict__ O1,
                                                 short* __restrict__ O2,
                                                 int M, int ntiles) {
    constexpr int BM = 128, BK = 32;
    constexpr int LDK = BK + 8;                 // 40 shorts = 80 B row stride
    __shared__ short As[BM * LDK];
    __shared__ short Bs[BN * LDK];

    const int tid = threadIdx.x;
    const int lane = tid & 63;
    const int wid = tid >> 6;
    const int bm = blockIdx.x / ntiles;
    const int bn = blockIdx.x % ntiles;
    const int m0 = bm * BM;
    const int n0 = bn * BN;

    constexpr int FM = (BN == 128) ? 4 : 2;     // 16-row frags per wave
    constexpr int FN = 4;                       // 16-col frags per wave (WN=64)
    constexpr int WM = FM * 16;                 // 64 or 32
    const int wm = (BN == 128) ? (wid >> 1) : wid;
    const int wn = (BN == 128) ? (wid & 1) : 0;

    f32x4 acc[FM][FN];
#pragma unroll
    for (int i = 0; i < FM; ++i)
#pragma unroll
        for (int j = 0; j < FN; ++j) acc[i][j] = (f32x4){0.f, 0.f, 0.f, 0.f};

    for (int k0 = 0; k0 < K; k0 += BK) {
        __syncthreads();
        if (AF32) {
            const float* A = (const float*)Avoid;
#pragma unroll
            for (int it = 0; it < BM / 32; ++it) {           // 32 rows/iter
                int r = it * 32 + (tid >> 3);
                int kq = tid & 7;                            // float4 slot
                int gr = m0 + r; if (gr >= M) gr = M - 1;
                const float4 v = *reinterpret_cast<const float4*>(
                    &A[(size_t)gr * K + k0 + kq * 4]);
                unsigned p0 = (unsigned)(unsigned short)f2b(v.x) |
                              ((unsigned)(unsigned short)f2b(v.y) << 16);
                unsigned p1 = (unsigned)(unsigned short)f2b(v.z) |
                              ((unsigned)(unsigned short)f2b(v.w) << 16);
                int2 w; w.x = (int)p0; w.y = (int)p1;
                *reinterpret_cast<int2*>(&As[r * LDK + kq * 4]) = w;
            }
        } else {
            const short* A = (const short*)Avoid;
#pragma unroll
            for (int it = 0; it < BM / 64; ++it) {           // 64 rows/iter
                int r = it * 64 + (tid >> 2);
                int kq = tid & 3;                            // 8-bf16 slot
                int gr = m0 + r; if (gr >= M) gr = M - 1;
                const int4 v = *reinterpret_cast<const int4*>(
                    &A[(size_t)gr * K + k0 + kq * 8]);
                *reinterpret_cast<int4*>(&As[r * LDK + kq * 8]) = v;
            }
        }
        // B tile: BN rows x BK bf16, 4 slots of 16B per row -> 64 rows/iter
#pragma unroll
        for (int it = 0; it < BN / 64; ++it) {
            int r = it * 64 + (tid >> 2);
            int kq = tid & 3;
            const int4 v = *reinterpret_cast<const int4*>(
                &Bt[(size_t)(n0 + r) * K + k0 + kq * 8]);
            *reinterpret_cast<int4*>(&Bs[r * LDK + kq * 8]) = v;
        }
        __syncthreads();

        short8v af[FM], bf[FN];
#pragma unroll
        for (int f = 0; f < FM; ++f)
            af[f] = *reinterpret_cast<const short8v*>(
                &As[(wm * WM + f * 16 + (lane & 15)) * LDK + (lane >> 4) * 8]);
#pragma unroll
        for (int f = 0; f < FN; ++f)
            bf[f] = *reinterpret_cast<const short8v*>(
                &Bs[(wn * 64 + f * 16 + (lane & 15)) * LDK + (lane >> 4) * 8]);
#pragma unroll
        for (int i = 0; i < FM; ++i)
#pragma unroll
            for (int j = 0; j < FN; ++j)
                acc[i][j] = __builtin_amdgcn_mfma_f32_16x16x32_bf16(
                    af[i], bf[j], acc[i][j], 0, 0, 0);
    }

    short* outp = (bn == 0) ? O0 : ((bn == 1) ? O1 : O2);
#pragma unroll
    for (int i = 0; i < FM; ++i)
#pragma unroll
        for (int j = 0; j < FN; ++j)
#pragma unroll
            for (int e = 0; e < 4; ++e) {
                int row = m0 + wm * WM + i * 16 + (lane >> 4) * 4 + e;
                int colt = wn * 64 + j * 16 + (lane & 15);
                if (row < M) outp[(size_t)row * BN + colt] = f2b(acc[i][j][e]);
            }
}

// ---------------------------------------------------------------------------
// CSR construction: histogram -> 2-level exclusive scan -> position scatter
// ---------------------------------------------------------------------------
__global__ __launch_bounds__(256) void hist_kernel(const int* __restrict__ row,
                                                   int* __restrict__ counts, int E) {
    int i = blockIdx.x * 256 + threadIdx.x;
    if (i < E) atomicAdd(&counts[row[i]], 1);
}

__global__ __launch_bounds__(256) void block_sums_kernel(const int* __restrict__ counts,
                                                         int* __restrict__ bsums, int n) {
    __shared__ int s[256];
    int tid = threadIdx.x;
    int i = blockIdx.x * 256 + tid;
    s[tid] = (i < n) ? counts[i] : 0;
    __syncthreads();
#pragma unroll
    for (int off = 128; off > 0; off >>= 1) {
        if (tid < off) s[tid] += s[tid + off];
        __syncthreads();
    }
    if (tid == 0) bsums[blockIdx.x] = s[0];
}

__global__ __launch_bounds__(64) void scan_bsums_kernel(int* __restrict__ bsums, int nb) {
    if (threadIdx.x == 0) {
        int a = 0;
        for (int i = 0; i < nb; ++i) {
            int t = bsums[i];
            bsums[i] = a;
            a += t;
        }
    }
}

__global__ __launch_bounds__(256) void scan_final_kernel(const int* __restrict__ counts,
                                                         const int* __restrict__ bsums,
                                                         int* __restrict__ rowptr,
                                                         int* __restrict__ cursor, int n) {
    __shared__ int s[256];
    int tid = threadIdx.x;
    int i = blockIdx.x * 256 + tid;
    int v = (i < n) ? counts[i] : 0;
    s[tid] = v;
    __syncthreads();
#pragma unroll
    for (int off = 1; off < 256; off <<= 1) {
        int t = (tid >= off) ? s[tid - off] : 0;
        __syncthreads();
        s[tid] += t;
        __syncthreads();
    }
    int excl = s[tid] - v + bsums[blockIdx.x];
    if (i < n) {
        rowptr[i] = excl;
        cursor[i] = excl;
        if (i == n - 1) rowptr[n] = excl + v;
    }
}

__global__ __launch_bounds__(256) void scatter_edges_kernel(const int* __restrict__ row,
                                                            const int* __restrict__ col,
                                                            const float* __restrict__ val,
                                                            int* __restrict__ cursor,
                                                            int* __restrict__ cols_s,
                                                            float* __restrict__ vals_s, int E) {
    int i = blockIdx.x * 256 + threadIdx.x;
    if (i < E) {
        int r = row[i];
        int p = atomicAdd(&cursor[r], 1);
        cols_s[p] = col[i];
        vals_s[p] = val[i];
    }
}

// ---------------------------------------------------------------------------
// Pull-based CSR spmm over bf16 X, one wave per row, fp32 accumulate/output.
// HIGH=false: Y = relu(spmm(X));  HIGH=true: Y = relu(X[row] - spmm(X)).
// ---------------------------------------------------------------------------
template <int H, bool HIGH>
__global__ __launch_bounds__(256) void spmm_csr(const int* __restrict__ rowptr,
                                                const int* __restrict__ cols,
                                                const float* __restrict__ vals,
                                                const short* __restrict__ X,
                                                float* __restrict__ Y, int n) {
    const int node = blockIdx.x * 4 + (threadIdx.x >> 6);
    const int lane = threadIdx.x & 63;
    if (node >= n) return;
    const int s = rowptr[node];
    const int e = rowptr[node + 1];

    float acc[H / 64];
#pragma unroll
    for (int q = 0; q < H / 64; ++q) acc[q] = 0.f;

    for (int b = s; b < e; b += 64) {
        const int idx = b + lane;
        int c = 0;
        float v = 0.f;
        if (idx < e) { c = cols[idx]; v = vals[idx]; }
        const int cnt = min(64, e - b);
        for (int j = 0; j < cnt; ++j) {
            const int cj = __shfl(c, j, 64);
            const float vj = __shfl(v, j, 64);
#pragma unroll
            for (int q = 0; q < H / 64; ++q)
                acc[q] += vj * b2f(X[(size_t)cj * H + q * 64 + lane]);
        }
    }

#pragma unroll
    for (int q = 0; q < H / 64; ++q) {
        float o;
        if (HIGH)
            o = b2f(X[(size_t)node * H + q * 64 + lane]) - acc[q];
        else
            o = acc[q];
        Y[(size_t)node * H + q * 64 + lane] = o > 0.f ? o : 0.f;
    }
}

// ---------------------------------------------------------------------------
__device__ __forceinline__ float wave_sum(float v) {
#pragma unroll
    for (int off = 32; off > 0; off >>= 1) v += __shfl_xor(v, off, 64);
    return v;
}
__device__ __forceinline__ float wave_max(float v) {
#pragma unroll
    for (int off = 32; off > 0; off >>= 1) v = fmaxf(v, __shfl_xor(v, off, 64));
    return v;
}

// ---------------------------------------------------------------------------
// Layer-1 fused attention+combine -> h (bf16).
// ---------------------------------------------------------------------------
__global__ __launch_bounds__(256) void att_combine1(const float* __restrict__ o_low,
                                                    const float* __restrict__ o_high,
                                                    const short* __restrict__ xm_b,
                                                    const float* __restrict__ a_low,
                                                    const float* __restrict__ a_high,
                                                    const float* __restrict__ a_mlp,
                                                    const float* __restrict__ av,
                                                    short* __restrict__ hb,
                                                    int n) {
    const int node = blockIdx.x * 4 + (threadIdx.x >> 6);
    const int lane = threadIdx.x & 63;
    if (node >= n) return;
    const size_t base = (size_t)node * HH;

    float ol0 = o_low[base + lane];
    float ol1 = o_low[base + 64 + lane];
    float oh0 = o_high[base + lane];
    float oh1 = o_high[base + 64 + lane];
    float om0 = fmaxf(b2f(xm_b[base + lane]), 0.f);
    float om1 = fmaxf(b2f(xm_b[base + 64 + lane]), 0.f);

    float dl = ol0 * a_low[lane] + ol1 * a_low[64 + lane];
    float dh = oh0 * a_high[lane] + oh1 * a_high[64 + lane];
    float dm = om0 * a_mlp[lane] + om1 * a_mlp[64 + lane];
    dl = wave_sum(dl);
    dh = wave_sum(dh);
    dm = wave_sum(dm);

    const float g0 = 1.f / (1.f + expf(-dl));
    const float g1 = 1.f / (1.f + expf(-dh));
    const float g2 = 1.f / (1.f + expf(-dm));
    float s0 = (g0 * av[0] + g1 * av[3] + g2 * av[6]) * (1.f / 3.f);
    float s1 = (g0 * av[1] + g1 * av[4] + g2 * av[7]) * (1.f / 3.f);
    float s2 = (g0 * av[2] + g1 * av[5] + g2 * av[8]) * (1.f / 3.f);
    float mx = fmaxf(s0, fmaxf(s1, s2));
    float e0 = expf(s0 - mx), e1 = expf(s1 - mx), e2 = expf(s2 - mx);
    float inv = 1.f / (e0 + e1 + e2);
    float at0 = e0 * inv, at1 = e1 * inv, at2 = e2 * inv;

    hb[base + lane]      = f2b(3.f * (at0 * ol0 + at1 * oh0 + at2 * om0));
    hb[base + 64 + lane] = f2b(3.f * (at0 * ol1 + at1 * oh1 + at2 * om1));
}

// ---------------------------------------------------------------------------
// Layer-2 fused attention+combine+log_softmax -> d_out (f32).
// ---------------------------------------------------------------------------
__global__ __launch_bounds__(256) void att_combine2(const float* __restrict__ o_low,
                                                    const float* __restrict__ o_high,
                                                    const short* __restrict__ xm_b,
                                                    const float* __restrict__ a_low,
                                                    const float* __restrict__ a_high,
                                                    const float* __restrict__ a_mlp,
                                                    const float* __restrict__ av,
                                                    float* __restrict__ out,
                                                    int n) {
    const int node = blockIdx.x * 4 + (threadIdx.x >> 6);
    const int lane = threadIdx.x & 63;
    if (node >= n) return;
    const size_t base = (size_t)node * CC;

    float ol = o_low[base + lane];
    float oh = o_high[base + lane];
    float om = fmaxf(b2f(xm_b[base + lane]), 0.f);

    float dl = wave_sum(ol * a_low[lane]);
    float dh = wave_sum(oh * a_high[lane]);
    float dm = wave_sum(om * a_mlp[lane]);

    const float g0 = 1.f / (1.f + expf(-dl));
    const float g1 = 1.f / (1.f + expf(-dh));
    const float g2 = 1.f / (1.f + expf(-dm));
    float s0 = (g0 * av[0] + g1 * av[3] + g2 * av[6]) * (1.f / 3.f);
    float s1 = (g0 * av[1] + g1 * av[4] + g2 * av[7]) * (1.f / 3.f);
    float s2 = (g0 * av[2] + g1 * av[5] + g2 * av[8]) * (1.f / 3.f);
    float mx3 = fmaxf(s0, fmaxf(s1, s2));
    float e0 = expf(s0 - mx3), e1 = expf(s1 - mx3), e2 = expf(s2 - mx3);
    float inv = 1.f / (e0 + e1 + e2);
    float at0 = e0 * inv, at1 = e1 * inv, at2 = e2 * inv;

    float o = 3.f * (at0 * ol + at1 * oh + at2 * om);

    float m = wave_max(o);
    float ex = expf(o - m);
    float su = wave_sum(ex);
    out[base + lane] = o - m - logf(su);
}

// ---------------------------------------------------------------------------
extern "C" void kernel_launch(void* const* d_in, const int* in_sizes, int n_in,
                              void* d_out, int out_size, void* d_ws, size_t ws_size,
                              hipStream_t stream) {
    const float* x    = (const float*)d_in[0];
    const int*   erow = (const int*)d_in[1];
    const int*   ecol = (const int*)d_in[2];
    const float* eval = (const float*)d_in[3];
    const float* Wl   = (const float*)d_in[4];
    const float* Wh   = (const float*)d_in[5];
    const float* Wm   = (const float*)d_in[6];
    const float* al   = (const float*)d_in[7];
    const float* ah   = (const float*)d_in[8];
    const float* am   = (const float*)d_in[9];
    const float* av   = (const float*)d_in[10];
    const float* Wl2  = (const float*)d_in[11];
    const float* Wh2  = (const float*)d_in[12];
    const float* Wm2  = (const float*)d_in[13];
    const float* al2  = (const float*)d_in[14];
    const float* ah2  = (const float*)d_in[15];
    const float* am2  = (const float*)d_in[16];
    const float* av2  = (const float*)d_in[17];
    float* out = (float*)d_out;

    const int E = in_sizes[1];
    const int N = NN;
    const size_t NH = (size_t)N * HH;

    float* ws    = (float*)d_ws;
    float* oLow  = ws;                 // N*HH f32 (L2 reuse: N*CC)
    float* oHigh = ws + NH;            // N*HH f32
    short* xb    = (short*)(ws + 2 * NH);
    short* xl_b  = xb;                 // N*HH bf16
    short* xh_b  = xb + NH;            // N*HH bf16
    short* xm_b  = xb + 2 * NH;        // N*HH bf16
    short* hb    = xb + 3 * NH;        // N*HH bf16
    short* Bt1   = hb + NH;            // 384*512 bf16
    short* Bt2   = Bt1 + 384 * 512;    // 192*128 bf16
    int*   ip    = (int*)(Bt2 + 192 * 128);
    int*   counts = ip;                // N
    int*   rowptr = ip + N;            // N+1
    int*   cursor = ip + 2 * N + 1;    // N
    int*   bsums  = ip + 3 * N + 1;    // 256
    int*   cols_s = ip + 3 * N + 1 + 256;  // E
    float* vals_s = (float*)(cols_s + E);  // E

    // L2 aliases (regions free by the time they're written)
    short* xl2_b = xb;                        // N*CC
    short* xh2_b = xb + (size_t)N * CC;       // N*CC
    short* xm2_b = xb + 2 * (size_t)N * CC;   // N*CC
    float* oLow2  = oLow;
    float* oHigh2 = oHigh;

    const int NB = (N + 255) / 256;
    const int EB = (E + 255) / 256;
    const int node_blocks = (N + 3) / 4;
    const int MT = (N + 127) / 128;

    // ---------------- CSR build + weight prep ----------------
    hipMemsetAsync(counts, 0, (size_t)N * sizeof(int), stream);
    hist_kernel<<<EB, 256, 0, stream>>>(erow, counts, E);
    block_sums_kernel<<<NB, 256, 0, stream>>>(counts, bsums, N);
    scan_bsums_kernel<<<1, 64, 0, stream>>>(bsums, NB);
    scan_final_kernel<<<NB, 256, 0, stream>>>(counts, bsums, rowptr, cursor, N);
    scatter_edges_kernel<<<EB, 256, 0, stream>>>(erow, ecol, eval, cursor, cols_s, vals_s, E);
    wprep<F_IN, HH><<<(3 * HH * (F_IN / 8) + 255) / 256, 256, 0, stream>>>(Wl, Wh, Wm, Bt1);
    wprep<HH, CC><<<(3 * CC * (HH / 8) + 255) / 256, 256, 0, stream>>>(Wl2, Wh2, Wm2, Bt2);

    // ---------------- Layer 1 ----------------
    gemm_mfma<F_IN, HH, true><<<MT * 3, 256, 0, stream>>>(x, Bt1, xl_b, xh_b, xm_b, N, 3);
    spmm_csr<HH, true><<<node_blocks, 256, 0, stream>>>(rowptr, cols_s, vals_s,
                                                        xh_b, oHigh, N);
    spmm_csr<HH, false><<<node_blocks, 256, 0, stream>>>(rowptr, cols_s, vals_s,
                                                         xl_b, oLow, N);
    att_combine1<<<node_blocks, 256, 0, stream>>>(oLow, oHigh, xm_b, al, ah, am, av, hb, N);

    // ---------------- Layer 2 ----------------
    gemm_mfma<HH, CC, false><<<MT * 3, 256, 0, stream>>>(hb, Bt2, xl2_b, xh2_b, xm2_b, N, 3);
    spmm_csr<CC, true><<<node_blocks, 256, 0, stream>>>(rowptr, cols_s, vals_s,
                                                        xh2_b, oHigh2, N);
    spmm_csr<CC, false><<<node_blocks, 256, 0, stream>>>(rowptr, cols_s, vals_s,
                                                         xl2_b, oLow2, N);
    att_combine2<<<node_blocks, 256, 0, stream>>>(oLow2, oHigh2, xm2_b,
                                                  al2, ah2, am2, av2, out, N);
}

// Round 4
// 352.476 us; speedup vs baseline: 4.1436x; 1.2366x over previous
//
#include <hip/hip_runtime.h>
#include <hip/hip_bf16.h>

// Problem constants (reference file)
#define NN 50000
#define F_IN 512
#define HH 128
#define CC 64

typedef __attribute__((ext_vector_type(8))) short short8v;   // 8 bf16 (4 VGPRs)
typedef __attribute__((ext_vector_type(4))) float f32x4;     // MFMA accumulator

__device__ __forceinline__ short f2b(float f) {
    unsigned u = __builtin_bit_cast(unsigned, f);
    unsigned r = (u + 0x7fffu + ((u >> 16) & 1u)) >> 16;     // RNE
    return (short)r;
}
__device__ __forceinline__ float b2f(short s) {
    unsigned u = ((unsigned)(unsigned short)s) << 16;
    return __builtin_bit_cast(float, u);
}
__device__ __forceinline__ float b2f_lo(unsigned p) {        // low 16 bits
    return __builtin_bit_cast(float, p << 16);
}
__device__ __forceinline__ float b2f_hi(unsigned p) {        // high 16 bits
    return __builtin_bit_cast(float, p & 0xffff0000u);
}

// ---------------------------------------------------------------------------
// Weight prep: Bt[n][k] = W_{n/OUTW}[k][n%OUTW]  (bf16, transposed + concat)
// ---------------------------------------------------------------------------
template <int K, int OUTW>
__global__ __launch_bounds__(256) void wprep(const float* __restrict__ W0,
                                             const float* __restrict__ W1,
                                             const float* __restrict__ W2,
                                             short* __restrict__ Bt) {
    const int id = blockIdx.x * 256 + threadIdx.x;
    const int nth = 3 * OUTW * (K / 8);
    if (id >= nth) return;
    const int n = id / (K / 8);
    const int kq = id % (K / 8);
    const int sel = n / OUTW;
    const int c = n % OUTW;
    const float* W = sel == 0 ? W0 : (sel == 1 ? W1 : W2);
    short v[8];
#pragma unroll
    for (int j = 0; j < 8; ++j) v[j] = f2b(W[(size_t)(kq * 8 + j) * OUTW + c]);
#pragma unroll
    for (int j = 0; j < 8; ++j) Bt[(size_t)n * K + kq * 8 + j] = v[j];
}

// ---------------------------------------------------------------------------
// Single-A-pass MFMA GEMM: C[M, NTOT] = A[M,K] @ Bt^T, split into O0/O1/O2
// (each M x NTOT/3, bf16). BM=128, BK=32, 512 threads (8 waves = 2x4).
// Per wave: 64 rows x (NTOT/4) cols. A fetched exactly once from HBM.
// ---------------------------------------------------------------------------
template <int K, int NTOT, bool AF32>
__global__ __launch_bounds__(512) void gemm_mfma(const void* __restrict__ Avoid,
                                                 const short* __restrict__ Bt,
                                                 short* __restrict__ O0,
                                                 short* __restrict__ O1,
                                                 short* __restrict__ O2,
                                                 int M) {
    constexpr int BM = 128, BK = 32;
    constexpr int LDK = BK + 8;                 // 40 shorts = 80 B row stride
    constexpr int BNout = NTOT / 3;             // 128 or 64
    constexpr int FM = 4;                       // 16-row frags per wave (64 rows)
    constexpr int FN = NTOT / 64;               // 16-col frags per wave (6 or 3)
    __shared__ short As[BM * LDK];
    __shared__ short Bs[NTOT * LDK];

    const int tid = threadIdx.x;
    const int lane = tid & 63;
    const int wid = tid >> 6;                   // 0..7
    const int wm = wid >> 2;                    // 0..1
    const int wn = wid & 3;                     // 0..3
    const int m0 = blockIdx.x * BM;

    f32x4 acc[FM][FN];
#pragma unroll
    for (int i = 0; i < FM; ++i)
#pragma unroll
        for (int j = 0; j < FN; ++j) acc[i][j] = (f32x4){0.f, 0.f, 0.f, 0.f};

    for (int k0 = 0; k0 < K; k0 += BK) {
        __syncthreads();
        // ---- stage A tile (BM x BK) ----
        if (AF32) {
            const float* A = (const float*)Avoid;
#pragma unroll
            for (int it = 0; it < 2; ++it) {               // 1024 float4 / 512
                int idx = it * 512 + tid;
                int r = idx >> 3;
                int kq = idx & 7;
                int gr = m0 + r; if (gr >= M) gr = M - 1;
                const float4 v = *reinterpret_cast<const float4*>(
                    &A[(size_t)gr * K + k0 + kq * 4]);
                unsigned p0 = (unsigned)(unsigned short)f2b(v.x) |
                              ((unsigned)(unsigned short)f2b(v.y) << 16);
                unsigned p1 = (unsigned)(unsigned short)f2b(v.z) |
                              ((unsigned)(unsigned short)f2b(v.w) << 16);
                int2 w; w.x = (int)p0; w.y = (int)p1;
                *reinterpret_cast<int2*>(&As[r * LDK + kq * 4]) = w;
            }
        } else {
            const short* A = (const short*)Avoid;
            {                                               // 512 int4 / 512
                int r = tid >> 2;
                int kq = tid & 3;
                int gr = m0 + r; if (gr >= M) gr = M - 1;
                const int4 v = *reinterpret_cast<const int4*>(
                    &A[(size_t)gr * K + k0 + kq * 8]);
                *reinterpret_cast<int4*>(&As[r * LDK + kq * 8]) = v;
            }
        }
        // ---- stage B tile (NTOT x BK) ----
#pragma unroll
        for (int p = 0; p < (NTOT * 4 + 511) / 512; ++p) {
            int idx = p * 512 + tid;
            if (idx < NTOT * 4) {
                int r = idx >> 2;
                int kq = idx & 3;
                const int4 v = *reinterpret_cast<const int4*>(
                    &Bt[(size_t)r * K + k0 + kq * 8]);
                *reinterpret_cast<int4*>(&Bs[r * LDK + kq * 8]) = v;
            }
        }
        __syncthreads();

        short8v af[FM], bf[FN];
#pragma unroll
        for (int f = 0; f < FM; ++f)
            af[f] = *reinterpret_cast<const short8v*>(
                &As[(wm * 64 + f * 16 + (lane & 15)) * LDK + (lane >> 4) * 8]);
#pragma unroll
        for (int f = 0; f < FN; ++f)
            bf[f] = *reinterpret_cast<const short8v*>(
                &Bs[(wn * (FN * 16) + f * 16 + (lane & 15)) * LDK + (lane >> 4) * 8]);
#pragma unroll
        for (int i = 0; i < FM; ++i)
#pragma unroll
            for (int j = 0; j < FN; ++j)
                acc[i][j] = __builtin_amdgcn_mfma_f32_16x16x32_bf16(
                    af[i], bf[j], acc[i][j], 0, 0, 0);
    }

#pragma unroll
    for (int i = 0; i < FM; ++i)
#pragma unroll
        for (int j = 0; j < FN; ++j) {
            int ct = wn * (FN * 16) + j * 16 + (lane & 15);
            int sel = ct / BNout;
            int cc = ct % BNout;
            short* outp = (sel == 0) ? O0 : ((sel == 1) ? O1 : O2);
#pragma unroll
            for (int e = 0; e < 4; ++e) {
                int row = m0 + wm * 64 + i * 16 + (lane >> 4) * 4 + e;
                if (row < M) outp[(size_t)row * BNout + cc] = f2b(acc[i][j][e]);
            }
        }
}

// ---------------------------------------------------------------------------
// CSR construction: histogram -> 2-level exclusive scan -> position scatter
// ---------------------------------------------------------------------------
__global__ __launch_bounds__(256) void hist_kernel(const int* __restrict__ row,
                                                   int* __restrict__ counts, int E) {
    int i = blockIdx.x * 256 + threadIdx.x;
    if (i < E) atomicAdd(&counts[row[i]], 1);
}

__global__ __launch_bounds__(256) void block_sums_kernel(const int* __restrict__ counts,
                                                         int* __restrict__ bsums, int n) {
    __shared__ int s[256];
    int tid = threadIdx.x;
    int i = blockIdx.x * 256 + tid;
    s[tid] = (i < n) ? counts[i] : 0;
    __syncthreads();
#pragma unroll
    for (int off = 128; off > 0; off >>= 1) {
        if (tid < off) s[tid] += s[tid + off];
        __syncthreads();
    }
    if (tid == 0) bsums[blockIdx.x] = s[0];
}

__global__ __launch_bounds__(64) void scan_bsums_kernel(int* __restrict__ bsums, int nb) {
    if (threadIdx.x == 0) {
        int a = 0;
        for (int i = 0; i < nb; ++i) {
            int t = bsums[i];
            bsums[i] = a;
            a += t;
        }
    }
}

__global__ __launch_bounds__(256) void scan_final_kernel(const int* __restrict__ counts,
                                                         const int* __restrict__ bsums,
                                                         int* __restrict__ rowptr,
                                                         int* __restrict__ cursor, int n) {
    __shared__ int s[256];
    int tid = threadIdx.x;
    int i = blockIdx.x * 256 + tid;
    int v = (i < n) ? counts[i] : 0;
    s[tid] = v;
    __syncthreads();
#pragma unroll
    for (int off = 1; off < 256; off <<= 1) {
        int t = (tid >= off) ? s[tid - off] : 0;
        __syncthreads();
        s[tid] += t;
        __syncthreads();
    }
    int excl = s[tid] - v + bsums[blockIdx.x];
    if (i < n) {
        rowptr[i] = excl;
        cursor[i] = excl;
        if (i == n - 1) rowptr[n] = excl + v;
    }
}

__global__ __launch_bounds__(256) void scatter_edges_kernel(const int* __restrict__ row,
                                                            const int* __restrict__ col,
                                                            const float* __restrict__ val,
                                                            int* __restrict__ cursor,
                                                            int* __restrict__ cols_s,
                                                            float* __restrict__ vals_s, int E) {
    int i = blockIdx.x * 256 + threadIdx.x;
    if (i < E) {
        int r = row[i];
        int p = atomicAdd(&cursor[r], 1);
        cols_s[p] = col[i];
        vals_s[p] = val[i];
    }
}

// ---------------------------------------------------------------------------
__device__ __forceinline__ float wave_sum(float v) {
#pragma unroll
    for (int off = 32; off > 0; off >>= 1) v += __shfl_xor(v, off, 64);
    return v;
}
__device__ __forceinline__ float wave_max(float v) {
#pragma unroll
    for (int off = 32; off > 0; off >>= 1) v = fmaxf(v, __shfl_xor(v, off, 64));
    return v;
}

// ---------------------------------------------------------------------------
// Layer-1 fused: dual CSR spmm (low & high) + attention + combine -> h (bf16).
// One wave per node; H=128 -> lane owns feat pair (2*lane, 2*lane+1).
// ---------------------------------------------------------------------------
__global__ __launch_bounds__(256) void spmm_att1(const int* __restrict__ rowptr,
                                                 const int* __restrict__ cols,
                                                 const float* __restrict__ vals,
                                                 const short* __restrict__ xl,
                                                 const short* __restrict__ xh,
                                                 const short* __restrict__ xm,
                                                 const float* __restrict__ a_low,
                                                 const float* __restrict__ a_high,
                                                 const float* __restrict__ a_mlp,
                                                 const float* __restrict__ av,
                                                 short* __restrict__ hb,
                                                 int n) {
    const int node = blockIdx.x * 4 + (threadIdx.x >> 6);
    const int lane = threadIdx.x & 63;
    if (node >= n) return;
    const unsigned* XL = (const unsigned*)xl;   // row = 64 u32 (feat pairs)
    const unsigned* XH = (const unsigned*)xh;
    const unsigned* XM = (const unsigned*)xm;

    const int s = rowptr[node];
    const int e = rowptr[node + 1];

    float l0 = 0.f, l1 = 0.f, h0 = 0.f, h1 = 0.f;
    for (int b = s; b < e; b += 64) {
        const int idx = b + lane;
        int c = 0;
        float v = 0.f;
        if (idx < e) { c = cols[idx]; v = vals[idx]; }
        const int cnt = min(64, e - b);
        for (int j = 0; j < cnt; ++j) {
            const int cj = __shfl(c, j, 64);
            const float vj = __shfl(v, j, 64);
            const unsigned pl = XL[(size_t)cj * 64 + lane];
            const unsigned ph = XH[(size_t)cj * 64 + lane];
            l0 += vj * b2f_lo(pl);
            l1 += vj * b2f_hi(pl);
            h0 += vj * b2f_lo(ph);
            h1 += vj * b2f_hi(ph);
        }
    }

    const unsigned xhn = XH[(size_t)node * 64 + lane];
    const unsigned xmn = XM[(size_t)node * 64 + lane];
    float ol0 = fmaxf(l0, 0.f);
    float ol1 = fmaxf(l1, 0.f);
    float oh0 = fmaxf(b2f_lo(xhn) - h0, 0.f);
    float oh1 = fmaxf(b2f_hi(xhn) - h1, 0.f);
    float om0 = fmaxf(b2f_lo(xmn), 0.f);
    float om1 = fmaxf(b2f_hi(xmn), 0.f);

    const float2 aL = ((const float2*)a_low)[lane];
    const float2 aH = ((const float2*)a_high)[lane];
    const float2 aM = ((const float2*)a_mlp)[lane];
    float dl = wave_sum(ol0 * aL.x + ol1 * aL.y);
    float dh = wave_sum(oh0 * aH.x + oh1 * aH.y);
    float dm = wave_sum(om0 * aM.x + om1 * aM.y);

    const float g0 = 1.f / (1.f + expf(-dl));
    const float g1 = 1.f / (1.f + expf(-dh));
    const float g2 = 1.f / (1.f + expf(-dm));
    float s0 = (g0 * av[0] + g1 * av[3] + g2 * av[6]) * (1.f / 3.f);
    float s1 = (g0 * av[1] + g1 * av[4] + g2 * av[7]) * (1.f / 3.f);
    float s2 = (g0 * av[2] + g1 * av[5] + g2 * av[8]) * (1.f / 3.f);
    float mx = fmaxf(s0, fmaxf(s1, s2));
    float e0 = expf(s0 - mx), e1 = expf(s1 - mx), e2 = expf(s2 - mx);
    float inv = 1.f / (e0 + e1 + e2);
    float at0 = e0 * inv, at1 = e1 * inv, at2 = e2 * inv;

    float ho0 = 3.f * (at0 * ol0 + at1 * oh0 + at2 * om0);
    float ho1 = 3.f * (at0 * ol1 + at1 * oh1 + at2 * om1);
    unsigned pk = (unsigned)(unsigned short)f2b(ho0) |
                  ((unsigned)(unsigned short)f2b(ho1) << 16);
    ((unsigned*)hb)[(size_t)node * 64 + lane] = pk;
}

// ---------------------------------------------------------------------------
// Layer-2 fused: dual CSR spmm + attention + combine + log_softmax -> out.
// One wave per node; C=64 -> lane owns one class.
// ---------------------------------------------------------------------------
__global__ __launch_bounds__(256) void spmm_att2(const int* __restrict__ rowptr,
                                                 const int* __restrict__ cols,
                                                 const float* __restrict__ vals,
                                                 const short* __restrict__ xl,
                                                 const short* __restrict__ xh,
                                                 const short* __restrict__ xm,
                                                 const float* __restrict__ a_low,
                                                 const float* __restrict__ a_high,
                                                 const float* __restrict__ a_mlp,
                                                 const float* __restrict__ av,
                                                 float* __restrict__ out,
                                                 int n) {
    const int node = blockIdx.x * 4 + (threadIdx.x >> 6);
    const int lane = threadIdx.x & 63;
    if (node >= n) return;

    const int s = rowptr[node];
    const int e = rowptr[node + 1];

    float accl = 0.f, acch = 0.f;
    for (int b = s; b < e; b += 64) {
        const int idx = b + lane;
        int c = 0;
        float v = 0.f;
        if (idx < e) { c = cols[idx]; v = vals[idx]; }
        const int cnt = min(64, e - b);
        for (int j = 0; j < cnt; ++j) {
            const int cj = __shfl(c, j, 64);
            const float vj = __shfl(v, j, 64);
            accl += vj * b2f(xl[(size_t)cj * 64 + lane]);
            acch += vj * b2f(xh[(size_t)cj * 64 + lane]);
        }
    }

    float ol = fmaxf(accl, 0.f);
    float oh = fmaxf(b2f(xh[(size_t)node * 64 + lane]) - acch, 0.f);
    float om = fmaxf(b2f(xm[(size_t)node * 64 + lane]), 0.f);

    float dl = wave_sum(ol * a_low[lane]);
    float dh = wave_sum(oh * a_high[lane]);
    float dm = wave_sum(om * a_mlp[lane]);

    const float g0 = 1.f / (1.f + expf(-dl));
    const float g1 = 1.f / (1.f + expf(-dh));
    const float g2 = 1.f / (1.f + expf(-dm));
    float s0 = (g0 * av[0] + g1 * av[3] + g2 * av[6]) * (1.f / 3.f);
    float s1 = (g0 * av[1] + g1 * av[4] + g2 * av[7]) * (1.f / 3.f);
    float s2 = (g0 * av[2] + g1 * av[5] + g2 * av[8]) * (1.f / 3.f);
    float mx3 = fmaxf(s0, fmaxf(s1, s2));
    float e0 = expf(s0 - mx3), e1 = expf(s1 - mx3), e2 = expf(s2 - mx3);
    float inv = 1.f / (e0 + e1 + e2);
    float at0 = e0 * inv, at1 = e1 * inv, at2 = e2 * inv;

    float o = 3.f * (at0 * ol + at1 * oh + at2 * om);

    float m = wave_max(o);
    float ex = expf(o - m);
    float su = wave_sum(ex);
    out[(size_t)node * 64 + lane] = o - m - logf(su);
}

// ---------------------------------------------------------------------------
extern "C" void kernel_launch(void* const* d_in, const int* in_sizes, int n_in,
                              void* d_out, int out_size, void* d_ws, size_t ws_size,
                              hipStream_t stream) {
    const float* x    = (const float*)d_in[0];
    const int*   erow = (const int*)d_in[1];
    const int*   ecol = (const int*)d_in[2];
    const float* eval = (const float*)d_in[3];
    const float* Wl   = (const float*)d_in[4];
    const float* Wh   = (const float*)d_in[5];
    const float* Wm   = (const float*)d_in[6];
    const float* al   = (const float*)d_in[7];
    const float* ah   = (const float*)d_in[8];
    const float* am   = (const float*)d_in[9];
    const float* av   = (const float*)d_in[10];
    const float* Wl2  = (const float*)d_in[11];
    const float* Wh2  = (const float*)d_in[12];
    const float* Wm2  = (const float*)d_in[13];
    const float* al2  = (const float*)d_in[14];
    const float* ah2  = (const float*)d_in[15];
    const float* am2  = (const float*)d_in[16];
    const float* av2  = (const float*)d_in[17];
    float* out = (float*)d_out;

    const int E = in_sizes[1];
    const int N = NN;
    const size_t NH = (size_t)N * HH;

    short* xb    = (short*)d_ws;
    short* xl_b  = xb;                 // N*HH bf16
    short* xh_b  = xb + NH;            // N*HH bf16
    short* xm_b  = xb + 2 * NH;        // N*HH bf16
    short* hb    = xb + 3 * NH;        // N*HH bf16
    short* Bt1   = hb + NH;            // 384*512 bf16
    short* Bt2   = Bt1 + 384 * 512;    // 192*128 bf16
    int*   ip    = (int*)(Bt2 + 192 * 128);
    int*   counts = ip;                // N
    int*   rowptr = ip + N;            // N+1
    int*   cursor = ip + 2 * N + 1;    // N
    int*   bsums  = ip + 3 * N + 1;    // 256
    int*   cols_s = ip + 3 * N + 1 + 256;  // E
    float* vals_s = (float*)(cols_s + E);  // E

    // Layer-2 aliases (xl/xh/xm regions dead after spmm_att1)
    short* xl2_b = xb;                        // N*CC
    short* xh2_b = xb + (size_t)N * CC;       // N*CC
    short* xm2_b = xb + 2 * (size_t)N * CC;   // N*CC

    const int NB = (N + 255) / 256;
    const int EB = (E + 255) / 256;
    const int node_blocks = (N + 3) / 4;
    const int MT = (N + 127) / 128;

    // ---------------- CSR build + weight prep ----------------
    hipMemsetAsync(counts, 0, (size_t)N * sizeof(int), stream);
    hist_kernel<<<EB, 256, 0, stream>>>(erow, counts, E);
    block_sums_kernel<<<NB, 256, 0, stream>>>(counts, bsums, N);
    scan_bsums_kernel<<<1, 64, 0, stream>>>(bsums, NB);
    scan_final_kernel<<<NB, 256, 0, stream>>>(counts, bsums, rowptr, cursor, N);
    scatter_edges_kernel<<<EB, 256, 0, stream>>>(erow, ecol, eval, cursor, cols_s, vals_s, E);
    wprep<F_IN, HH><<<(3 * HH * (F_IN / 8) + 255) / 256, 256, 0, stream>>>(Wl, Wh, Wm, Bt1);
    wprep<HH, CC><<<(3 * CC * (HH / 8) + 255) / 256, 256, 0, stream>>>(Wl2, Wh2, Wm2, Bt2);

    // ---------------- Layer 1 ----------------
    gemm_mfma<F_IN, 384, true><<<MT, 512, 0, stream>>>(x, Bt1, xl_b, xh_b, xm_b, N);
    spmm_att1<<<node_blocks, 256, 0, stream>>>(rowptr, cols_s, vals_s,
                                               xl_b, xh_b, xm_b, al, ah, am, av, hb, N);

    // ---------------- Layer 2 ----------------
    gemm_mfma<HH, 192, false><<<MT, 512, 0, stream>>>(hb, Bt2, xl2_b, xh2_b, xm2_b, N);
    spmm_att2<<<node_blocks, 256, 0, stream>>>(rowptr, cols_s, vals_s,
                                               xl2_b, xh2_b, xm2_b,
                                               al2, ah2, am2, av2, out, N);
}